// Round 1
// 168.628 us; speedup vs baseline: 1.0639x; 1.0639x over previous
//
#include <hip/hip_runtime.h>
#include <hip/hip_bf16.h>

#define NN   50000
#define EE   1600000
#define FIN  128
#define FOUT 64
#define BETA  0.5f
#define ALPHA 0.2f
#define SBW    256          // src rows per super-bucket
#define NB2    196          // ceil(NN/SBW)
#define RCAP   9000         // fixed region capacity (mean 8163 + ~9 sigma)
#define PGRID  400          // partition blocks (run density: 4000/196 ~ 20 recs/run)
#define PCHUNK 4000         // EE/PGRID exact; 4 edges/thread at 1024 threads
#define CAP2   9008         // csr LDS record cache (72 KB; covers full RCAP)
#define XS     136          // gemm X LDS stride (bf16 elems, 16B-aligned rows)

typedef __attribute__((ext_vector_type(8))) short short8;
typedef __attribute__((ext_vector_type(8))) unsigned short ushort8v;
typedef __attribute__((ext_vector_type(4))) float float4v;

__device__ __forceinline__ float load_any(const void* p, long i, int isf32) {
    if (isf32) return ((const float*)p)[i];
    unsigned int b = ((unsigned int)(((const unsigned short*)p)[i])) << 16;
    return __uint_as_float(b);
}

__device__ __forceinline__ unsigned short f32_to_bf16_rne(float f) {
    unsigned int b = __float_as_uint(f);
    return (unsigned short)((b + 0x7FFF + ((b >> 16) & 1)) >> 16);
}

__device__ __forceinline__ float bf16_to_f32(unsigned short u) {
    return __uint_as_float(((unsigned int)u) << 16);
}

// ---------------------------------------------------------------------------
// Kernel 0: sampled dtype detection. flags[t]=1 means fp32.
// ---------------------------------------------------------------------------
__global__ __launch_bounds__(256) void detect_kernel(
    const void* inp, const void* Mv, const void* W, const void* a, int* flags)
{
    const void* ptrs[4] = { inp, Mv, W, a };
    const long  cnts[4] = { (long)NN * FIN, (long)EE, (long)FIN * FOUT, 2L * FOUT };
    const int t = blockIdx.x;
    const unsigned short* p = (const unsigned short*)ptrs[t];
    const long half = cnts[t] >> 1;
    long step = half / 256; if (step == 0) step = 1;
    const long pos = 2 * (((long)threadIdx.x * step) % half);

    const float v = bf16_to_f32(p[pos]);
    const int bad = (isnan(v) || fabsf(v) > 1e4f) ? 1 : 0;

    __shared__ int sbad[256];
    sbad[threadIdx.x] = bad;
    __syncthreads();
    for (int s = 128; s > 0; s >>= 1) {
        if (threadIdx.x < (unsigned)s) sbad[threadIdx.x] |= sbad[threadIdx.x + s];
        __syncthreads();
    }
    if (threadIdx.x == 0) flags[t] = sbad[0];
}

// ---------------------------------------------------------------------------
// Kernel 0b: one-time W transpose -> Wt[n][k] bf16 (16 KB). Block 0 also
// zeroes bcur (saves the hipMemsetAsync dispatch).
// ---------------------------------------------------------------------------
__global__ __launch_bounds__(256) void wt_kernel(
    const void* __restrict__ W, const int* __restrict__ flags,
    unsigned short* __restrict__ Wt, int* __restrict__ bcur)
{
    if (blockIdx.x == 0 && threadIdx.x < NB2) bcur[threadIdx.x] = 0;
    const int fW = flags[2];
    const int i = blockIdx.x * 256 + threadIdx.x;
    if (i < FIN * FOUT) {
        const int k = i >> 6, n = i & 63;           // read W coalesced
        Wt[n * FIN + k] = f32_to_bf16_rne(load_any(W, i, fW));
    }
}

// ---------------------------------------------------------------------------
// Kernel 1: MFMA gemm (R11-validated). 16 rows/block; X staged via one 16 B
// vector load/thread; B-fragments direct from global Wt (L1-hot 16 KB).
// ---------------------------------------------------------------------------
__global__ __launch_bounds__(256) void mfma_gemm_kernel(
    const void* __restrict__ inp,
    const unsigned short* __restrict__ Wt,   // bf16 [64][128]
    const void* __restrict__ a,
    const int* __restrict__ flags,
    unsigned short* __restrict__ h,
    float* __restrict__ s1,
    float* __restrict__ s2)
{
    __shared__ unsigned short Xs[16 * XS];   // 4.25 KB
    __shared__ float part1[4][16];
    __shared__ float part2[4][16];

    const int tid  = threadIdx.x;
    const int wave = tid >> 6;
    const int lane = tid & 63;
    const int quad = lane >> 4;
    const int col  = lane & 15;
    const int rb   = blockIdx.x * 16;

    const int fI = flags[0], fA = flags[3];

    {
        const int r = tid >> 4, k8 = (tid & 15) * 8;
        if (!fI) {
            const unsigned short* src = (const unsigned short*)inp + (long)(rb + r) * FIN + k8;
            *(ushort8v*)&Xs[r * XS + k8] = *(const ushort8v*)src;
        } else {
            const float* src = (const float*)inp + (long)(rb + r) * FIN + k8;
            ushort8v v;
            #pragma unroll
            for (int j = 0; j < 8; ++j) v[j] = f32_to_bf16_rne(src[j]);
            *(ushort8v*)&Xs[r * XS + k8] = v;
        }
    }
    __syncthreads();

    const int nb = wave * 16;
    float4v acc = { 0.f, 0.f, 0.f, 0.f };
    #pragma unroll
    for (int k0 = 0; k0 < FIN; k0 += 32) {
        const short8 af = *(const short8*)&Xs[col * XS + k0 + quad * 8];
        const short8 bf = *(const short8*)&Wt[(long)(nb + col) * FIN + k0 + quad * 8];
        acc = __builtin_amdgcn_mfma_f32_16x16x32_bf16(af, bf, acc, 0, 0, 0);
    }

    #pragma unroll
    for (int r = 0; r < 4; ++r)
        h[(long)(rb + quad * 4 + r) * FOUT + nb + col] = f32_to_bf16_rne(acc[r]);

    const float a1 = load_any(a, nb + col, fA);
    const float a2 = load_any(a, 64 + nb + col, fA);
    #pragma unroll
    for (int r = 0; r < 4; ++r) {
        float v1 = acc[r] * a1;
        float v2 = acc[r] * a2;
        #pragma unroll
        for (int o = 1; o < 16; o <<= 1) {
            v1 += __shfl_xor(v1, o, 64);
            v2 += __shfl_xor(v2, o, 64);
        }
        if (col == 0) {
            part1[wave][quad * 4 + r] = v1;
            part2[wave][quad * 4 + r] = v2;
        }
    }
    __syncthreads();
    if (tid < 16) {
        s1[rb + tid] = part1[0][tid] + part1[1][tid] + part1[2][tid] + part1[3][tid];
        s2[rb + tid] = part2[0][tid] + part2[1][tid] + part2[2][tid] + part2[3][tid];
    }
}

// ---------------------------------------------------------------------------
// Kernel 2: partition into 196 super-buckets with FIXED regions (b*RCAP).
// 1024-thread blocks x 400 = 6400 waves; R11 run density; normal stores
// (R12 lesson: NT scattered stores bypass L2 write coalescing -> 3x amp).
// Record: src<<32 | dst<<16 | bf16(edge_e).
// ---------------------------------------------------------------------------
__global__ __launch_bounds__(1024) void partition_kernel(
    const int* __restrict__ edge,
    const void* __restrict__ Mv,
    const int* __restrict__ flags,
    const float* __restrict__ s1,
    const float* __restrict__ s2,
    int* __restrict__ bcur,              // [NB2], zeroed; per-bucket count
    unsigned long long* __restrict__ recs)
{
    __shared__ int lcnt[NB2];
    __shared__ int lbase[NB2];
    const int tid = threadIdx.x;
    const int fM = flags[1];
    const int e0 = blockIdx.x * PCHUNK;

    if (tid < NB2) lcnt[tid] = 0;
    __syncthreads();

    int srcs[4], dsts[4];
    float mvs[4];
    #pragma unroll
    for (int k = 0; k < 4; ++k) {
        const int e = e0 + tid + 1024 * k;
        const bool ok = (tid + 1024 * k) < PCHUNK;
        srcs[k] = ok ? edge[e] : -1;
        dsts[k] = ok ? edge[EE + e] : 0;
        mvs[k]  = ok ? load_any(Mv, e, fM) : 0.f;
    }
    #pragma unroll
    for (int k = 0; k < 4; ++k)
        if (srcs[k] >= 0) atomicAdd(&lcnt[srcs[k] >> 8], 1);
    __syncthreads();

    if (tid < NB2) {
        const int c = lcnt[tid];
        const int o = c ? atomicAdd(&bcur[tid], c) : 0;
        lbase[tid] = tid * RCAP + o;
        lcnt[tid] = 0;                 // reuse as rank counter
    }
    __syncthreads();

    float ss1[4], ss2[4];
    #pragma unroll
    for (int k = 0; k < 4; ++k) {
        ss1[k] = (srcs[k] >= 0) ? s1[srcs[k]] : 0.f;
        ss2[k] = (srcs[k] >= 0) ? s2[dsts[k]] : 0.f;
    }
    #pragma unroll
    for (int k = 0; k < 4; ++k) {
        if (srcs[k] < 0) continue;
        const float bias = mvs[k] * BETA + (1.f - BETA);
        const float x  = ss1[k] + bias * ss2[k];
        const float lr = x > 0.f ? x : ALPHA * x;
        const float ee = __expf(lr);
        const int b = srcs[k] >> 8;
        const int r = atomicAdd(&lcnt[b], 1);
        const int pos = lbase[b] + r;
        if (pos < (b + 1) * RCAP)      // graceful guard (P ~ 1e-17)
            recs[pos] = ((unsigned long long)(unsigned)srcs[k] << 32)
                      | ((unsigned long long)(unsigned)dsts[k] << 16)
                      | (unsigned long long)f32_to_bf16_rne(ee);
    }
}

// ---------------------------------------------------------------------------
// Kernel 3: per-super-bucket CSR finalize + row ranges.
// R1: 1024 threads/block (was 256) — 8 strided iterations instead of 32 and
// 16 waves to hide global-load + LDS-atomic latency (kernel is latency-bound:
// only 196 blocks exist). CAP2 raised to cover full RCAP (74 KB LDS).
// ---------------------------------------------------------------------------
__global__ __launch_bounds__(1024) void bucket_csr_kernel(
    const int* __restrict__ bcur,
    const unsigned long long* __restrict__ recs,
    unsigned int* __restrict__ pairs,
    int* __restrict__ rowbeg,
    int* __restrict__ rowend)
{
    __shared__ unsigned long long lrec[CAP2];   // 72 KB
    __shared__ int cnt[SBW];
    __shared__ int off[SBW];
    __shared__ int wsum[4];
    const int b    = blockIdx.x;
    const int tid  = threadIdx.x;
    const int rb   = b * SBW;
    const int beg  = b * RCAP;

    int n = bcur[b]; if (n > RCAP) n = RCAP;

    if (tid < SBW) cnt[tid] = 0;
    __syncthreads();

    for (int j = tid; j < n; j += 1024) {
        const unsigned long long rec = recs[beg + j];
        if (j < CAP2) lrec[j] = rec;
        atomicAdd(&cnt[(int)(rec >> 32) - rb], 1);
    }
    __syncthreads();

    int c = 0, x = 0;
    if (tid < SBW) {                    // waves 0..3 fully active (no intra-wave divergence)
        const int lane = tid & 63;
        c = cnt[tid];
        x = c;
        #pragma unroll
        for (int o = 1; o < 64; o <<= 1) {
            int y = __shfl_up(x, o, 64);
            if (lane >= o) x += y;
        }
        if (lane == 63) wsum[tid >> 6] = x;
    }
    __syncthreads();
    if (tid < SBW) {
        const int wave = tid >> 6;
        int wb = 0;
        for (int w = 0; w < wave; ++w) wb += wsum[w];
        const int myoff = wb + x - c;
        off[tid] = myoff;
        const int row = rb + tid;
        if (row < NN) {
            rowbeg[row] = beg + myoff;
            rowend[row] = beg + myoff + c;
        }
        cnt[tid] = 0;                  // reuse as rank counter
    }
    __syncthreads();

    for (int j = tid; j < n; j += 1024) {
        const unsigned long long rec = (j < CAP2) ? lrec[j] : recs[beg + j];
        const int r = (int)(rec >> 32) - rb;
        const int rank = atomicAdd(&cnt[r], 1);
        pairs[beg + off[r] + rank] = (unsigned int)(rec & 0xFFFFFFFFu);
    }
}

// ---------------------------------------------------------------------------
// Kernel 4: CSR-vector SpMM, fused finalize. One wave per src row.
// R1: 8 lanes/edge x ushort8 (16 B gathers, was 16 lanes x 8 B) — half the
// load instructions, 8 edges in flight per wave, same gather bytes.
// ---------------------------------------------------------------------------
__global__ __launch_bounds__(256) void spmm_kernel(
    const int* __restrict__ rowbeg,
    const int* __restrict__ rowend,
    const unsigned int* __restrict__ pairs,
    const unsigned short* __restrict__ h,   // bf16 [NN, FOUT]
    const int* __restrict__ flags,
    void* __restrict__ out)
{
    const int wave = threadIdx.x >> 6;
    const int lane = threadIdx.x & 63;
    const int g    = lane >> 3;          // which of 8 in-flight edges
    const int sl   = lane & 7;           // features 8*sl .. 8*sl+7
    const int row  = blockIdx.x * 4 + wave;

    const int beg = rowbeg[row];
    const int end = rowend[row];

    float acc0 = 0.f, acc1 = 0.f, acc2 = 0.f, acc3 = 0.f;
    float acc4 = 0.f, acc5 = 0.f, acc6 = 0.f, acc7 = 0.f;
    float rsum = 0.f;
    int j = beg;
    for (; j + 15 < end; j += 16) {
        const unsigned int u0 = pairs[j + g];
        const unsigned int u1 = pairs[j + 8 + g];
        const ushort8v h0 = *(const ushort8v*)&h[(long)(u0 >> 16) * FOUT + 8 * sl];
        const ushort8v h1 = *(const ushort8v*)&h[(long)(u1 >> 16) * FOUT + 8 * sl];
        const float v0 = bf16_to_f32((unsigned short)(u0 & 0xFFFFu));
        const float v1 = bf16_to_f32((unsigned short)(u1 & 0xFFFFu));
        rsum += v0 + v1;
        acc0 = fmaf(v0, bf16_to_f32(h0[0]), acc0); acc0 = fmaf(v1, bf16_to_f32(h1[0]), acc0);
        acc1 = fmaf(v0, bf16_to_f32(h0[1]), acc1); acc1 = fmaf(v1, bf16_to_f32(h1[1]), acc1);
        acc2 = fmaf(v0, bf16_to_f32(h0[2]), acc2); acc2 = fmaf(v1, bf16_to_f32(h1[2]), acc2);
        acc3 = fmaf(v0, bf16_to_f32(h0[3]), acc3); acc3 = fmaf(v1, bf16_to_f32(h1[3]), acc3);
        acc4 = fmaf(v0, bf16_to_f32(h0[4]), acc4); acc4 = fmaf(v1, bf16_to_f32(h1[4]), acc4);
        acc5 = fmaf(v0, bf16_to_f32(h0[5]), acc5); acc5 = fmaf(v1, bf16_to_f32(h1[5]), acc5);
        acc6 = fmaf(v0, bf16_to_f32(h0[6]), acc6); acc6 = fmaf(v1, bf16_to_f32(h1[6]), acc6);
        acc7 = fmaf(v0, bf16_to_f32(h0[7]), acc7); acc7 = fmaf(v1, bf16_to_f32(h1[7]), acc7);
    }
    for (; j < end; j += 8) {
        if (j + g < end) {
            const unsigned int u = pairs[j + g];
            const ushort8v hv = *(const ushort8v*)&h[(long)(u >> 16) * FOUT + 8 * sl];
            const float v = bf16_to_f32((unsigned short)(u & 0xFFFFu));
            rsum += v;
            acc0 = fmaf(v, bf16_to_f32(hv[0]), acc0);
            acc1 = fmaf(v, bf16_to_f32(hv[1]), acc1);
            acc2 = fmaf(v, bf16_to_f32(hv[2]), acc2);
            acc3 = fmaf(v, bf16_to_f32(hv[3]), acc3);
            acc4 = fmaf(v, bf16_to_f32(hv[4]), acc4);
            acc5 = fmaf(v, bf16_to_f32(hv[5]), acc5);
            acc6 = fmaf(v, bf16_to_f32(hv[6]), acc6);
            acc7 = fmaf(v, bf16_to_f32(hv[7]), acc7);
        }
    }

    // combine the 8 edge-groups (lanes within a group hold distinct features)
    #pragma unroll
    for (int o = 8; o < 64; o <<= 1) {
        rsum += __shfl_xor(rsum, o, 64);
        acc0 += __shfl_xor(acc0, o, 64);
        acc1 += __shfl_xor(acc1, o, 64);
        acc2 += __shfl_xor(acc2, o, 64);
        acc3 += __shfl_xor(acc3, o, 64);
        acc4 += __shfl_xor(acc4, o, 64);
        acc5 += __shfl_xor(acc5, o, 64);
        acc6 += __shfl_xor(acc6, o, 64);
        acc7 += __shfl_xor(acc7, o, 64);
    }

    if (g == 0) {
        const float inv = 1.f / rsum;
        float q0 = acc0 * inv, q1 = acc1 * inv, q2 = acc2 * inv, q3 = acc3 * inv;
        float q4 = acc4 * inv, q5 = acc5 * inv, q6 = acc6 * inv, q7 = acc7 * inv;
        q0 = q0 > 0.f ? q0 : (__expf(q0) - 1.f);
        q1 = q1 > 0.f ? q1 : (__expf(q1) - 1.f);
        q2 = q2 > 0.f ? q2 : (__expf(q2) - 1.f);
        q3 = q3 > 0.f ? q3 : (__expf(q3) - 1.f);
        q4 = q4 > 0.f ? q4 : (__expf(q4) - 1.f);
        q5 = q5 > 0.f ? q5 : (__expf(q5) - 1.f);
        q6 = q6 > 0.f ? q6 : (__expf(q6) - 1.f);
        q7 = q7 > 0.f ? q7 : (__expf(q7) - 1.f);
        if (flags[0]) {
            float4* o = (float4*)((float*)out + (long)row * FOUT + 8 * sl);
            o[0] = make_float4(q0, q1, q2, q3);
            o[1] = make_float4(q4, q5, q6, q7);
        } else {
            ushort8v ov;
            ov[0] = f32_to_bf16_rne(q0); ov[1] = f32_to_bf16_rne(q1);
            ov[2] = f32_to_bf16_rne(q2); ov[3] = f32_to_bf16_rne(q3);
            ov[4] = f32_to_bf16_rne(q4); ov[5] = f32_to_bf16_rne(q5);
            ov[6] = f32_to_bf16_rne(q6); ov[7] = f32_to_bf16_rne(q7);
            *(ushort8v*)((unsigned short*)out + (long)row * FOUT + 8 * sl) = ov;
        }
    }
}

extern "C" void kernel_launch(void* const* d_in, const int* in_sizes, int n_in,
                              void* d_out, int out_size, void* d_ws, size_t ws_size,
                              hipStream_t stream) {
    const void* inp  = d_in[0];
    const void* Mv   = d_in[1];
    const void* W    = d_in[2];
    const void* a    = d_in[3];
    const int*  edge = (const int*)d_in[4];

    // ws: flags | Wt bf16[64*128] | h bf16[NN*64] | s1[NN] | s2[NN] |
    //     rowbeg[NN] | rowend[NN] | bcur[NB2] | pairs u32[NB2*RCAP] | recs u64[NB2*RCAP]
    char* p = (char*)d_ws;
    int*                flags  = (int*)p;            p += 256;
    unsigned short*     Wt     = (unsigned short*)p; p += ((size_t)FOUT * FIN * 2 + 255) / 256 * 256;
    unsigned short*     h      = (unsigned short*)p; p += ((size_t)NN * FOUT * 2 + 255) / 256 * 256;
    float*              s1     = (float*)p;          p += ((size_t)NN * 4 + 255) / 256 * 256;
    float*              s2     = (float*)p;          p += ((size_t)NN * 4 + 255) / 256 * 256;
    int*                rowbeg = (int*)p;            p += ((size_t)NN * 4 + 255) / 256 * 256;
    int*                rowend = (int*)p;            p += ((size_t)NN * 4 + 255) / 256 * 256;
    int*                bcur   = (int*)p;            p += ((size_t)NB2 * 4 + 255) / 256 * 256;
    unsigned int*       pairs  = (unsigned int*)p;   p += ((size_t)NB2 * RCAP * 4 + 255) / 256 * 256;
    unsigned long long* recs   = (unsigned long long*)p;

    detect_kernel<<<4, 256, 0, stream>>>(inp, Mv, W, a, flags);
    wt_kernel<<<(FIN * FOUT + 255) / 256, 256, 0, stream>>>(W, flags, Wt, bcur);
    mfma_gemm_kernel<<<NN / 16, 256, 0, stream>>>(inp, Wt, a, flags, h, s1, s2);
    partition_kernel<<<PGRID, 1024, 0, stream>>>(edge, Mv, flags, s1, s2, bcur, recs);
    bucket_csr_kernel<<<NB2, 1024, 0, stream>>>(bcur, recs, pairs, rowbeg, rowend);
    spmm_kernel<<<NN / 4, 256, 0, stream>>>(rowbeg, rowend, pairs, h, flags, d_out);
}